// Round 13
// baseline (109.332 us; speedup 1.0000x reference)
//
#include <hip/hip_runtime.h>
#include <math.h>

#define RENDER 256
#define IMG_H 480
#define IMG_W 640
#define NV 2048
#define NF 4096
#define FACE_SLICES 16
#define FACES_PER_SLICE (NF / FACE_SLICES)       // 256
#define TILES 256                                 // 16x16 tiles of 16x16 px
#define N_UNITS (TILES * FACE_SLICES)             // 4096 units

#define SIGMA_INV 2.0f                            // 1/SIGMA, SIGMA=0.5
#define CAP 13.815510557964274f                   // -log(1e-6)
#define LOG2E 1.4426950408889634f
#define ZK 2.8853900817779268f                    // SIGMA_INV * LOG2E
#define CAP2 19.931568569324174f                  // CAP * LOG2E
// 16x16 tile: pixel-center half-diagonal r = 7.5*sqrt(2) = 10.607 px; scaled
// d has Lipschitz const <= ZK, so tile variation <= 10.607*ZK = 30.6.
//   cap  everywhere: z_c > CAP2 + 30.6 = 50.5  -> 50.8 (margin)
//   skip everywhere: z_pix < -26 (2e-8/face) -> z_c < -56.6
#define THR_CAP2  50.8f
#define THR_SKIP2 -56.6f
// wave-uniform runtime saturation thresholds (exact z values, not bounds):
//   all z >= 19.94  -> min(sp2,CAP2) == CAP2 exactly (sp2>=CAP2 at 19.9315)
//   all z <  -24    -> sp2 < 8.6e-8; over <=4096 faces -> <=3.5e-4 in lp
#define Z_ALLCAP 19.94f
#define Z_ALLLOW -24.0f

// ws layout:
//   [0, 192KB)       fdata : 4096 faces * 12 floats (3 edges * {A,B,C,pad})
//   [192KB, 448KB)   logp  : 65536 floats (log2-domain)
#define WS_FD_OFF    0
#define WS_LOGP_OFF  (192 * 1024)

// ---------------- kernel 1: fused setup ----------------------------------
// blocks 0..15   : SE3 exp (redundant per thread) + project all verts into
//                  LDS (redundant per block) + per-face edge coefficients
//                  (prescaled by ZK into log2 domain)
// blocks 16..271 : zero logp; block 16 thread 0 zeros out[0]
__global__ __launch_bounds__(256) void k_prep(const float* __restrict__ dof,
                                              const float* __restrict__ verts,
                                              const int* __restrict__ faces,
                                              const float* __restrict__ Km,
                                              float* __restrict__ fdata,
                                              float* __restrict__ logp,
                                              float* __restrict__ out) {
    if (blockIdx.x >= 16) {
        logp[(blockIdx.x - 16) * 256 + threadIdx.x] = 0.0f;
        if (blockIdx.x == 16 && threadIdx.x == 0) out[0] = 0.0f;
        return;
    }

    __shared__ float sxy[NV * 2];   // 16 KB projected verts

    float v0 = dof[0], v1 = dof[1], v2 = dof[2];
    float w0 = dof[3], w1 = dof[4], w2 = dof[5];
    float th2 = w0 * w0 + w1 * w1 + w2 * w2;
    float th = sqrtf(th2 + 1e-30f);
    bool small = th < 1e-4f;
    float th_s = small ? 1.0f : th;
    float th2_s = small ? 1.0f : th2;
    float A = small ? (1.0f - th2 / 6.0f) : (sinf(th_s) / th_s);
    float B = small ? (0.5f - th2 / 24.0f) : ((1.0f - cosf(th_s)) / th2_s);
    float C = small ? (1.0f / 6.0f - th2 / 120.0f)
                    : ((th_s - sinf(th_s)) / (th2_s * th_s));
    float Kx[9] = {0.0f, -w2, w1, w2, 0.0f, -w0, -w1, w0, 0.0f};
    float w[3] = {w0, w1, w2};
    float R[9], V[9];
    for (int i = 0; i < 3; i++)
        for (int j = 0; j < 3; j++) {
            float K2 = w[i] * w[j] - (i == j ? th2 : 0.0f);
            float id = (i == j) ? 1.0f : 0.0f;
            R[i * 3 + j] = id + A * Kx[i * 3 + j] + B * K2;
            V[i * 3 + j] = id + B * Kx[i * 3 + j] + C * K2;
        }
    float t0 = V[0] * v0 + V[1] * v1 + V[2] * v2;
    float t1 = V[3] * v0 + V[4] * v1 + V[5] * v2;
    float t2 = V[6] * v0 + V[7] * v1 + V[8] * v2;
    float K00 = Km[0], K01 = Km[1], K02 = Km[2];
    float K10 = Km[3], K11 = Km[4], K12 = Km[5];
    float K20 = Km[6], K21 = Km[7], K22 = Km[8];
    const float scale = 256.0f / 640.0f;

    for (int n = threadIdx.x; n < NV; n += 256) {
        float vx = verts[n * 3], vy = verts[n * 3 + 1], vz = verts[n * 3 + 2];
        float cx = R[0] * vx + R[1] * vy + R[2] * vz + t0;
        float cy = R[3] * vx + R[4] * vy + R[5] * vz + t1;
        float cz = R[6] * vx + R[7] * vy + R[8] * vz + t2;
        float u = K00 * cx + K01 * cy + K02 * cz;
        float v = K10 * cx + K11 * cy + K12 * cz;
        float ww = K20 * cx + K21 * cy + K22 * cz;
        float rw = __builtin_amdgcn_rcpf(ww) * scale;   // rel err ~1e-7: 2e-5 px
        sxy[n * 2]     = u * rw;
        sxy[n * 2 + 1] = v * rw;
    }
    __syncthreads();

    int f = blockIdx.x * 256 + threadIdx.x;
    int i0 = faces[f * 3], i1 = faces[f * 3 + 1], i2 = faces[f * 3 + 2];
    float x0 = sxy[i0 * 2], y0 = sxy[i0 * 2 + 1];
    float x1 = sxy[i1 * 2], y1 = sxy[i1 * 2 + 1];
    float x2 = sxy[i2 * 2], y2 = sxy[i2 * 2 + 1];
    float ex[3] = {x1 - x0, x2 - x1, x0 - x2};
    float ey[3] = {y1 - y0, y2 - y1, y0 - y2};
    float ax[3] = {x0, x1, x2};
    float ay[3] = {y0, y1, y2};
    float area2 = ex[0] * (-ey[2]) - ey[0] * (-ex[2]);
    float sgn = (area2 >= 0.0f) ? 1.0f : -1.0f;
    float* o = fdata + f * 12;
    for (int k = 0; k < 3; k++) {
        float elen = sqrtf(ex[k] * ex[k] + ey[k] * ey[k]) + 1e-9f;
        float c0 = ex[k] * ay[k] - ey[k] * ax[k];
        float inv = sgn / elen * ZK;       // prescale into log2 domain
        o[k * 4 + 0] = ex[k] * inv;        // A (py coeff)
        o[k * 4 + 1] = -ey[k] * inv;       // B (px coeff)
        o[k * 4 + 2] = -c0 * inv;          // C
        o[k * 4 + 3] = 0.0f;
    }
}

// ---------------- kernel 2: tiled + culled soft rasterization ------------
// 4096 blocks x 256 threads (4 waves). block -> unit via odd-multiplier
// hash (bijection mod 4096). unit = tile*16 + slice.
// Phase 1: classify 256 faces at tile center, ballot-compact survivors.
// Phase 2: survivors split across the 4 waves; each lane evaluates 4 px.
//          NEW (R13): wave-uniform saturation skip — if ALL 256 px of the
//          tile have z >= 19.94 the face contributes exactly -CAP2/px (no
//          trans); if all z < -24 it contributes < 8.6e-8/px (dropped).
//          Big triangles make both cases common; trans pipe was the
//          per-eval cost floor (R5-R12 invariant ~29 us).
// Phase 3: LDS reduction of wave partials, 1 atomic per pixel.
__global__ __launch_bounds__(256) void k_raster(const float* __restrict__ fdata,
                                                float* __restrict__ logp) {
    __shared__ float s_data[4096];   // survivors (3120) / reduction (4096)
    __shared__ int s_n;
    __shared__ int s_ncap;
    const int tid = threadIdx.x;
    if (tid == 0) { s_n = 0; s_ncap = 0; }
    __syncthreads();

    const int unit = (blockIdx.x * 2053) & (N_UNITS - 1);
    const int tile = unit >> 4;            // 0..255
    const int slice = unit & 15;
    const int tileX = tile & 15;
    const int tileY = tile >> 4;
    const float cx = tileX * 16 + 8.0f;
    const float cy = tileY * 16 + 8.0f;
    const float4* __restrict__ fd4 = (const float4*)fdata;

    // ---- phase 1: cull + ballot-compact (1 face per thread) ----
    {
        int f = slice * FACES_PER_SLICE + tid;
        float4 e0 = fd4[f * 3 + 0];
        float4 e1 = fd4[f * 3 + 1];
        float4 e2 = fd4[f * 3 + 2];
        float d0 = fmaf(e0.y, cx, fmaf(e0.x, cy, e0.z));
        float d1 = fmaf(e1.y, cx, fmaf(e1.x, cy, e1.z));
        float d2 = fmaf(e2.y, cx, fmaf(e2.x, cy, e2.z));
        float dmin = fminf(d0, fminf(d1, d2));
        bool capped = dmin > THR_CAP2;
        bool live = (!capped) && (dmin > THR_SKIP2);
        unsigned long long mcap = __ballot(capped);
        unsigned long long mliv = __ballot(live);
        int lane = tid & 63;
        int base = 0;
        if (lane == 0) {
            base = atomicAdd(&s_n, __popcll(mliv));
            atomicAdd(&s_ncap, __popcll(mcap));
        }
        base = __shfl(base, 0, 64);
        if (live) {
            int pos = base + __popcll(mliv & ((1ull << lane) - 1ull));
            float4* dst = (float4*)(s_data + pos * 12);
            dst[0] = e0; dst[1] = e1; dst[2] = e2;
        }
    }
    __syncthreads();

    const int n = s_n;
    const int ncap = s_ncap;
    if (n == 0 && ncap == 0) return;     // empty unit: no contribution

    // ---- phase 2: wave-split survivor eval, 4 px/lane ----
    const int wv = tid >> 6;
    const int lane = tid & 63;
    const int row = lane >> 2;                       // 0..15
    const int col0 = lane & 3;                       // + {0,4,8,12}
    const float py = (float)(tileY * 16 + row) + 0.5f;
    const float px0 = (float)(tileX * 16 + col0) + 0.5f;

    float acc[4] = {0.0f, 0.0f, 0.0f, 0.0f};
    const float4* sd = (const float4*)s_data;
    if (wv < n) {
        float4 c0 = sd[wv * 3 + 0], c1 = sd[wv * 3 + 1], c2 = sd[wv * 3 + 2];
        for (int i = wv; i < n; i += 4) {
            // prefetch slot i+4 (slot <= 259 -> float < 3120 < 4096; value
            // discarded at loop exit when i+4 >= n)
            float4 n0 = sd[(i + 4) * 3 + 0];
            float4 n1 = sd[(i + 4) * 3 + 1];
            float4 n2 = sd[(i + 4) * 3 + 2];
            float t0p = fmaf(c0.x, py, c0.z);  // py-terms shared by the 4 px
            float t1p = fmaf(c1.x, py, c1.z);
            float t2p = fmaf(c2.x, py, c2.z);
            float z[4];
            #pragma unroll
            for (int k = 0; k < 4; ++k) {
                float px = px0 + (float)(4 * k);
                z[k] = fminf(fmaf(c0.y, px, t0p),
                       fminf(fmaf(c1.y, px, t1p), fmaf(c2.y, px, t2p)));
            }
            float zmin = fminf(fminf(z[0], z[1]), fminf(z[2], z[3]));
            float zmax = fmaxf(fmaxf(z[0], z[1]), fmaxf(z[2], z[3]));
            // wave-uniform saturation tests over the whole 256-px tile
            unsigned long long notAllCap = __ballot(zmin < Z_ALLCAP);
            if (notAllCap == 0ull) {
                acc[0] -= CAP2; acc[1] -= CAP2;
                acc[2] -= CAP2; acc[3] -= CAP2;
            } else {
                unsigned long long anyAbove = __ballot(zmax >= Z_ALLLOW);
                if (anyAbove != 0ull) {
                    #pragma unroll
                    for (int k = 0; k < 4; ++k) {
                        float e = __builtin_amdgcn_exp2f(z[k]);
                        float sp2 = __builtin_amdgcn_logf(1.0f + e);
                        acc[k] -= fminf(sp2, CAP2);
                    }
                }
                // else: all z < -24 across the tile -> dropped (<=3.5e-4 lp)
            }
            c0 = n0; c1 = n1; c2 = n2;
        }
    }

    // ---- phase 3: reduce 4 wave-partials in LDS, 1 atomic per px ----
    __syncthreads();                      // all waves done reading survivors
    {
        int base = wv * 1024 + row * 16 + col0;      // tile-local pixel index
        s_data[base + 0]  = acc[0];
        s_data[base + 4]  = acc[1];
        s_data[base + 8]  = acc[2];
        s_data[base + 12] = acc[3];
    }
    __syncthreads();
    {
        int p = tid;                                  // tile-local pixel 0..255
        float v = s_data[p] + s_data[1024 + p] + s_data[2048 + p] +
                  s_data[3072 + p] - CAP2 * (float)ncap;
        int iyp = tileY * 16 + (p >> 4);
        int ixp = tileX * 16 + (p & 15);
        atomicAdd(&logp[iyp * RENDER + ixp], v);
    }
}

// ---------------- kernel 3: resize-nearest + crop + SSE loss -------------
__global__ __launch_bounds__(256) void k_final(const float* __restrict__ logp,
                                               const float* __restrict__ mask,
                                               float* __restrict__ out) {
    int idx = blockIdx.x * 256 + threadIdx.x;   // 0 .. 307199
    int r = idx / IMG_W;
    int c = idx - r * IMG_W;
    // jax nearest: in = floor((out+0.5)*256/640) == (2*out+1)/5 exactly
    int ir = (2 * r + 1) / 5;
    int ic = (2 * c + 1) / 5;
    // logp is log2-domain: si = 1 - 2^lp2
    float si = 1.0f - __builtin_amdgcn_exp2f(logp[ir * RENDER + ic]);
    out[1 + idx] = si;
    float diff = si - mask[idx];
    float d2 = diff * diff;
    #pragma unroll
    for (int off = 32; off > 0; off >>= 1) d2 += __shfl_down(d2, off, 64);
    __shared__ float sred[4];
    int lane = threadIdx.x & 63;
    int wv = threadIdx.x >> 6;
    if (lane == 0) sred[wv] = d2;
    __syncthreads();
    if (threadIdx.x == 0)
        atomicAdd(out, sred[0] + sred[1] + sred[2] + sred[3]);
}

extern "C" void kernel_launch(void* const* d_in, const int* in_sizes, int n_in,
                              void* d_out, int out_size, void* d_ws, size_t ws_size,
                              hipStream_t stream) {
    const float* dof   = (const float*)d_in[0];
    const float* verts = (const float*)d_in[1];
    const int*   faces = (const int*)d_in[2];
    const float* Km    = (const float*)d_in[3];
    const float* mask  = (const float*)d_in[4];
    float* out = (float*)d_out;

    char* ws = (char*)d_ws;
    float* fdata = (float*)(ws + WS_FD_OFF);
    float* logp  = (float*)(ws + WS_LOGP_OFF);

    k_prep<<<272, 256, 0, stream>>>(dof, verts, faces, Km, fdata, logp, out);
    k_raster<<<N_UNITS, 256, 0, stream>>>(fdata, logp);
    k_final<<<(IMG_H * IMG_W) / 256, 256, 0, stream>>>(logp, mask, out);
}

// Round 14
// 104.727 us; speedup vs baseline: 1.0440x; 1.0440x over previous
//
#include <hip/hip_runtime.h>
#include <math.h>

#define RENDER 256
#define IMG_H 480
#define IMG_W 640
#define NV 2048
#define NF 4096
#define FACE_SLICES 16
#define FACES_PER_SLICE (NF / FACE_SLICES)       // 256
#define TILES 256                                 // 16x16 tiles of 16x16 px
#define N_UNITS (TILES * FACE_SLICES)             // 4096 units

#define SIGMA_INV 2.0f                            // 1/SIGMA, SIGMA=0.5
#define CAP 13.815510557964274f                   // -log(1e-6)
#define LOG2E 1.4426950408889634f
#define ZK 2.8853900817779268f                    // SIGMA_INV * LOG2E
#define CAP2 19.931568569324174f                  // CAP * LOG2E
// 16x16 tile: pixel-center half-diagonal r = 7.5*sqrt(2) = 10.607 px; scaled
// d has Lipschitz const <= ZK, so tile variation <= 10.607*ZK = 30.6.
//   cap  everywhere: z_c > CAP2 + 30.6 = 50.5  -> 50.8 (margin)
//   skip everywhere: z_pix < -26 (2e-8/face) -> z_c < -56.6
#define THR_CAP2  50.8f
#define THR_SKIP2 -56.6f

// ws layout:
//   [0, 192KB)       fdata : 4096 faces * 12 floats (3 edges * {A,B,C,pad})
//   [192KB, 448KB)   logp  : 65536 floats (log2-domain)
#define WS_FD_OFF    0
#define WS_LOGP_OFF  (192 * 1024)

// ---------------- kernel 1: fused setup ----------------------------------
// blocks 0..15   : SE3 exp (redundant per thread) + project all verts into
//                  LDS (redundant per block) + per-face edge coefficients
//                  (prescaled by ZK into log2 domain)
// blocks 16..271 : zero logp; block 16 thread 0 zeros out[0]
__global__ __launch_bounds__(256) void k_prep(const float* __restrict__ dof,
                                              const float* __restrict__ verts,
                                              const int* __restrict__ faces,
                                              const float* __restrict__ Km,
                                              float* __restrict__ fdata,
                                              float* __restrict__ logp,
                                              float* __restrict__ out) {
    if (blockIdx.x >= 16) {
        logp[(blockIdx.x - 16) * 256 + threadIdx.x] = 0.0f;
        if (blockIdx.x == 16 && threadIdx.x == 0) out[0] = 0.0f;
        return;
    }

    __shared__ float sxy[NV * 2];   // 16 KB projected verts

    float v0 = dof[0], v1 = dof[1], v2 = dof[2];
    float w0 = dof[3], w1 = dof[4], w2 = dof[5];
    float th2 = w0 * w0 + w1 * w1 + w2 * w2;
    float th = sqrtf(th2 + 1e-30f);
    bool small = th < 1e-4f;
    float th_s = small ? 1.0f : th;
    float th2_s = small ? 1.0f : th2;
    float A = small ? (1.0f - th2 / 6.0f) : (sinf(th_s) / th_s);
    float B = small ? (0.5f - th2 / 24.0f) : ((1.0f - cosf(th_s)) / th2_s);
    float C = small ? (1.0f / 6.0f - th2 / 120.0f)
                    : ((th_s - sinf(th_s)) / (th2_s * th_s));
    float Kx[9] = {0.0f, -w2, w1, w2, 0.0f, -w0, -w1, w0, 0.0f};
    float w[3] = {w0, w1, w2};
    float R[9], V[9];
    for (int i = 0; i < 3; i++)
        for (int j = 0; j < 3; j++) {
            float K2 = w[i] * w[j] - (i == j ? th2 : 0.0f);
            float id = (i == j) ? 1.0f : 0.0f;
            R[i * 3 + j] = id + A * Kx[i * 3 + j] + B * K2;
            V[i * 3 + j] = id + B * Kx[i * 3 + j] + C * K2;
        }
    float t0 = V[0] * v0 + V[1] * v1 + V[2] * v2;
    float t1 = V[3] * v0 + V[4] * v1 + V[5] * v2;
    float t2 = V[6] * v0 + V[7] * v1 + V[8] * v2;
    float K00 = Km[0], K01 = Km[1], K02 = Km[2];
    float K10 = Km[3], K11 = Km[4], K12 = Km[5];
    float K20 = Km[6], K21 = Km[7], K22 = Km[8];
    const float scale = 256.0f / 640.0f;

    for (int n = threadIdx.x; n < NV; n += 256) {
        float vx = verts[n * 3], vy = verts[n * 3 + 1], vz = verts[n * 3 + 2];
        float cx = R[0] * vx + R[1] * vy + R[2] * vz + t0;
        float cy = R[3] * vx + R[4] * vy + R[5] * vz + t1;
        float cz = R[6] * vx + R[7] * vy + R[8] * vz + t2;
        float u = K00 * cx + K01 * cy + K02 * cz;
        float v = K10 * cx + K11 * cy + K12 * cz;
        float ww = K20 * cx + K21 * cy + K22 * cz;
        float rw = __builtin_amdgcn_rcpf(ww) * scale;   // rel err ~1e-7: 2e-5 px
        sxy[n * 2]     = u * rw;
        sxy[n * 2 + 1] = v * rw;
    }
    __syncthreads();

    int f = blockIdx.x * 256 + threadIdx.x;
    int i0 = faces[f * 3], i1 = faces[f * 3 + 1], i2 = faces[f * 3 + 2];
    float x0 = sxy[i0 * 2], y0 = sxy[i0 * 2 + 1];
    float x1 = sxy[i1 * 2], y1 = sxy[i1 * 2 + 1];
    float x2 = sxy[i2 * 2], y2 = sxy[i2 * 2 + 1];
    float ex[3] = {x1 - x0, x2 - x1, x0 - x2};
    float ey[3] = {y1 - y0, y2 - y1, y0 - y2};
    float ax[3] = {x0, x1, x2};
    float ay[3] = {y0, y1, y2};
    float area2 = ex[0] * (-ey[2]) - ey[0] * (-ex[2]);
    float sgn = (area2 >= 0.0f) ? 1.0f : -1.0f;
    float* o = fdata + f * 12;
    for (int k = 0; k < 3; k++) {
        float elen = sqrtf(ex[k] * ex[k] + ey[k] * ey[k]) + 1e-9f;
        float c0 = ex[k] * ay[k] - ey[k] * ax[k];
        float inv = sgn / elen * ZK;       // prescale into log2 domain
        o[k * 4 + 0] = ex[k] * inv;        // A (py coeff)
        o[k * 4 + 1] = -ey[k] * inv;       // B (px coeff)
        o[k * 4 + 2] = -c0 * inv;          // C
        o[k * 4 + 3] = 0.0f;
    }
}

// ---------------- kernel 2: tiled + culled soft rasterization ------------
// 4096 blocks x 256 threads (4 waves). block -> unit via odd-multiplier
// hash (bijection mod 4096) so heavy central tiles scatter across CUs.
// unit = tile*16 + slice; tile = 16x16 px, slice = 256 faces.
// Phase 1: 256 threads classify the slice's 256 faces at tile center,
//          ballot-compact survivor coefficients into LDS.
// Phase 2: survivors split across the 4 waves (wave w takes i = w mod 4);
//          each lane evaluates 4 pixels (x+{0,4,8,12}) so one wave-iter
//          serves 256 px -> 1/4 the LDS reads of 1-px/thread, while heavy
//          units' serial chains are n/4.
// Phase 3: LDS reduction of the 4 per-wave partials, 1 atomic per pixel.
//          Wave w's partial for tile-local pixel p lives at
//          s_data[w*1024 + p]; lane l, sub-pixel k -> p = (l>>2)*16+(l&3)+4k.
__global__ __launch_bounds__(256) void k_raster(const float* __restrict__ fdata,
                                                float* __restrict__ logp) {
    // 16 KB, dual use:
    //   survivors: slots 0..259 of 12 floats  (3120 floats)
    //   reduction: 4 waves * 1024 tile-local-pixel floats (4096 floats)
    __shared__ float s_data[4096];
    __shared__ int s_n;
    __shared__ int s_ncap;
    const int tid = threadIdx.x;
    if (tid == 0) { s_n = 0; s_ncap = 0; }
    __syncthreads();

    const int unit = (blockIdx.x * 2053) & (N_UNITS - 1);
    const int tile = unit >> 4;            // 0..255
    const int slice = unit & 15;
    const int tileX = tile & 15;
    const int tileY = tile >> 4;
    const float cx = tileX * 16 + 8.0f;
    const float cy = tileY * 16 + 8.0f;
    const float4* __restrict__ fd4 = (const float4*)fdata;

    // ---- phase 1: cull + ballot-compact (1 face per thread) ----
    {
        int f = slice * FACES_PER_SLICE + tid;
        float4 e0 = fd4[f * 3 + 0];
        float4 e1 = fd4[f * 3 + 1];
        float4 e2 = fd4[f * 3 + 2];
        float d0 = fmaf(e0.y, cx, fmaf(e0.x, cy, e0.z));
        float d1 = fmaf(e1.y, cx, fmaf(e1.x, cy, e1.z));
        float d2 = fmaf(e2.y, cx, fmaf(e2.x, cy, e2.z));
        float dmin = fminf(d0, fminf(d1, d2));
        bool capped = dmin > THR_CAP2;
        bool live = (!capped) && (dmin > THR_SKIP2);
        unsigned long long mcap = __ballot(capped);
        unsigned long long mliv = __ballot(live);
        int lane = tid & 63;
        int base = 0;
        if (lane == 0) {
            base = atomicAdd(&s_n, __popcll(mliv));
            atomicAdd(&s_ncap, __popcll(mcap));
        }
        base = __shfl(base, 0, 64);
        if (live) {
            int pos = base + __popcll(mliv & ((1ull << lane) - 1ull));
            float4* dst = (float4*)(s_data + pos * 12);
            dst[0] = e0; dst[1] = e1; dst[2] = e2;
        }
    }
    __syncthreads();

    const int n = s_n;
    const int ncap = s_ncap;
    if (n == 0 && ncap == 0) return;     // empty unit: no contribution

    // ---- phase 2: wave-split survivor eval, 4 px/lane ----
    const int wv = tid >> 6;
    const int lane = tid & 63;
    const int row = lane >> 2;                       // 0..15
    const int col0 = lane & 3;                       // + {0,4,8,12}
    const float py = (float)(tileY * 16 + row) + 0.5f;
    const float px0 = (float)(tileX * 16 + col0) + 0.5f;

    float acc[4] = {0.0f, 0.0f, 0.0f, 0.0f};
    const float4* sd = (const float4*)s_data;
    if (wv < n) {
        float4 c0 = sd[wv * 3 + 0], c1 = sd[wv * 3 + 1], c2 = sd[wv * 3 + 2];
        for (int i = wv; i < n; i += 4) {
            // prefetch slot i+4 (slot <= 259 -> float < 3120 < 4096; value
            // discarded at loop exit when i+4 >= n)
            float4 n0 = sd[(i + 4) * 3 + 0];
            float4 n1 = sd[(i + 4) * 3 + 1];
            float4 n2 = sd[(i + 4) * 3 + 2];
            float t0p = fmaf(c0.x, py, c0.z);  // py-terms shared by the 4 px
            float t1p = fmaf(c1.x, py, c1.z);
            float t2p = fmaf(c2.x, py, c2.z);
            #pragma unroll
            for (int k = 0; k < 4; ++k) {
                float px = px0 + (float)(4 * k);
                float z = fminf(fmaf(c0.y, px, t0p),
                          fminf(fmaf(c1.y, px, t1p), fmaf(c2.y, px, t2p)));
                float e = __builtin_amdgcn_exp2f(z);
                float sp2 = __builtin_amdgcn_logf(1.0f + e);   // log2(1+2^z)
                acc[k] -= fminf(sp2, CAP2);
            }
            c0 = n0; c1 = n1; c2 = n2;
        }
    }

    // ---- phase 3: reduce 4 wave-partials in LDS, 1 atomic per px ----
    __syncthreads();                      // all waves done reading survivors
    {
        int base = wv * 1024 + row * 16 + col0;      // tile-local pixel index
        s_data[base + 0]  = acc[0];
        s_data[base + 4]  = acc[1];
        s_data[base + 8]  = acc[2];
        s_data[base + 12] = acc[3];
    }
    __syncthreads();
    {
        int p = tid;                                  // tile-local pixel 0..255
        float v = s_data[p] + s_data[1024 + p] + s_data[2048 + p] +
                  s_data[3072 + p] - CAP2 * (float)ncap;
        int iyp = tileY * 16 + (p >> 4);
        int ixp = tileX * 16 + (p & 15);
        atomicAdd(&logp[iyp * RENDER + ixp], v);
    }
}

// ---------------- kernel 3: resize-nearest + crop + SSE loss -------------
__global__ __launch_bounds__(256) void k_final(const float* __restrict__ logp,
                                               const float* __restrict__ mask,
                                               float* __restrict__ out) {
    int idx = blockIdx.x * 256 + threadIdx.x;   // 0 .. 307199
    int r = idx / IMG_W;
    int c = idx - r * IMG_W;
    // jax nearest: in = floor((out+0.5)*256/640) == (2*out+1)/5 exactly
    int ir = (2 * r + 1) / 5;
    int ic = (2 * c + 1) / 5;
    // logp is log2-domain: si = 1 - 2^lp2
    float si = 1.0f - __builtin_amdgcn_exp2f(logp[ir * RENDER + ic]);
    out[1 + idx] = si;
    float diff = si - mask[idx];
    float d2 = diff * diff;
    #pragma unroll
    for (int off = 32; off > 0; off >>= 1) d2 += __shfl_down(d2, off, 64);
    __shared__ float sred[4];
    int lane = threadIdx.x & 63;
    int wv = threadIdx.x >> 6;
    if (lane == 0) sred[wv] = d2;
    __syncthreads();
    if (threadIdx.x == 0)
        atomicAdd(out, sred[0] + sred[1] + sred[2] + sred[3]);
}

extern "C" void kernel_launch(void* const* d_in, const int* in_sizes, int n_in,
                              void* d_out, int out_size, void* d_ws, size_t ws_size,
                              hipStream_t stream) {
    const float* dof   = (const float*)d_in[0];
    const float* verts = (const float*)d_in[1];
    const int*   faces = (const int*)d_in[2];
    const float* Km    = (const float*)d_in[3];
    const float* mask  = (const float*)d_in[4];
    float* out = (float*)d_out;

    char* ws = (char*)d_ws;
    float* fdata = (float*)(ws + WS_FD_OFF);
    float* logp  = (float*)(ws + WS_LOGP_OFF);

    k_prep<<<272, 256, 0, stream>>>(dof, verts, faces, Km, fdata, logp, out);
    k_raster<<<N_UNITS, 256, 0, stream>>>(fdata, logp);
    k_final<<<(IMG_H * IMG_W) / 256, 256, 0, stream>>>(logp, mask, out);
}